// Round 11
// baseline (597.573 us; speedup 1.0000x reference)
//
#include <hip/hip_runtime.h>
#include <hip/hip_bf16.h>
#include <cstdint>

#define B_TOK 8192
#define DIN   1024
#define HID   4096
#define CLS   1000
#define CPAD  1024
#define NE    8
#define PAIR_CAP 18432           // 16384 + 8*256, multiple of 256
#define PART_BLOCKS 2048

typedef __attribute__((ext_vector_type(8))) short short8;
typedef __attribute__((ext_vector_type(4))) float floatx4;

__device__ __forceinline__ unsigned short f2bf(float f) {
  unsigned int u = __builtin_bit_cast(unsigned int, f);
  u += 0x7fffu + ((u >> 16) & 1u);   // RNE
  return (unsigned short)(u >> 16);
}

__device__ __forceinline__ float bf2f(unsigned short u) {
  return __builtin_bit_cast(float, (unsigned int)u << 16);
}

__device__ __forceinline__ void gload16(const void* g, void* l) {
  __builtin_amdgcn_global_load_lds(
      (const __attribute__((address_space(1))) void*)(uintptr_t)g,
      (__attribute__((address_space(3))) void*)(unsigned int)(uintptr_t)l,
      16, 0, 0);
}

#define BARRIER()  asm volatile("s_barrier" ::: "memory")
#define VMCNT8()   asm volatile("s_waitcnt vmcnt(8)" ::: "memory")
#define VMCNT0()   asm volatile("s_waitcnt vmcnt(0)" ::: "memory")
#define LGKMCNT0() asm volatile("s_waitcnt lgkmcnt(0)" ::: "memory")

// swizzled LDS read: 16B at (row, byte-in-row), XOR-swizzle on 16B slot
__device__ __forceinline__ short8 ldsrd(const unsigned short* buf, int row, int bir) {
  const char* p = (const char*)buf + row * 128 + (bir ^ ((row & 7) << 4));
  return *(const short8*)p;
}

// ---------------- gating: one wave per token (fused x -> bf16 cast; NO global atomics) ----------------
__global__ void k_gate(const float* __restrict__ x, const float* __restrict__ Wg,
                       const float* __restrict__ bg,
                       float* __restrict__ part, int* __restrict__ topk_e,
                       float* __restrict__ topk_w, ushort4* __restrict__ xb4) {
  int tok = (blockIdx.x * blockDim.x + threadIdx.x) >> 6;
  int lane = threadIdx.x & 63;
  __shared__ float psum[NE];
  if (threadIdx.x < NE) psum[threadIdx.x] = 0.f;
  __syncthreads();

  float acc[NE];
#pragma unroll
  for (int e = 0; e < NE; e++) acc[e] = 0.f;
  const float4* xr4 = (const float4*)(x + (size_t)tok * DIN);
#pragma unroll
  for (int i = 0; i < 4; i++) {
    int d4 = lane + i * 64;
    float4 v = xr4[d4];
    ushort4 o;
    o.x = f2bf(v.x); o.y = f2bf(v.y); o.z = f2bf(v.z); o.w = f2bf(v.w);
    xb4[(size_t)tok * (DIN / 4) + d4] = o;
    float vs[4] = {v.x, v.y, v.z, v.w};
#pragma unroll
    for (int c = 0; c < 4; c++) {
      const float4* wr4 = (const float4*)(Wg + (size_t)(d4 * 4 + c) * NE);
      float4 wa = wr4[0], wb = wr4[1];
      float xv = vs[c];
      acc[0] += xv * wa.x; acc[1] += xv * wa.y; acc[2] += xv * wa.z; acc[3] += xv * wa.w;
      acc[4] += xv * wb.x; acc[5] += xv * wb.y; acc[6] += xv * wb.z; acc[7] += xv * wb.w;
    }
  }
#pragma unroll
  for (int e = 0; e < NE; e++)
    for (int off = 32; off; off >>= 1) acc[e] += __shfl_xor(acc[e], off);

  if (lane == 0) {
    float p[NE];
    float m = -1e30f;
#pragma unroll
    for (int e = 0; e < NE; e++) { p[e] = acc[e] + bg[e]; m = fmaxf(m, p[e]); }
    float s = 0.f;
#pragma unroll
    for (int e = 0; e < NE; e++) { p[e] = expf(p[e] - m); s += p[e]; }
    float inv = 1.f / s;
#pragma unroll
    for (int e = 0; e < NE; e++) p[e] *= inv;
    int e0 = 0;
#pragma unroll
    for (int e = 1; e < NE; e++) if (p[e] > p[e0]) e0 = e;
    int e1 = -1;
#pragma unroll
    for (int e = 0; e < NE; e++) {
      if (e == e0) continue;
      if (e1 < 0 || p[e] > p[e1]) e1 = e;
    }
    float wi = 1.f / (p[e0] + p[e1]);
    topk_e[tok * 2] = e0;  topk_e[tok * 2 + 1] = e1;
    topk_w[tok * 2] = p[e0] * wi;  topk_w[tok * 2 + 1] = p[e1] * wi;
#pragma unroll
    for (int e = 0; e < NE; e++) atomicAdd(&psum[e], p[e]);   // LDS only
  }
  __syncthreads();
  if (threadIdx.x < NE) part[blockIdx.x * NE + threadIdx.x] = psum[threadIdx.x];
}

// ---------------- setup: histogram counts, offsets (256-pad), cursors, lb_loss, dummy fill ----------------
__global__ void k_setup(const int* __restrict__ topk_e, int* __restrict__ offsets_pad,
                        int* __restrict__ cursor, const float* __restrict__ part,
                        int* __restrict__ pair_token, float* __restrict__ out_lb) {
  __shared__ int scnt[NE];
  __shared__ int soff[NE + 1];
  __shared__ float ssum[NE];
  int t = threadIdx.x;            // 1024 threads
  int lane = t & 63;
  if (t < NE) { scnt[t] = 0; ssum[t] = 0.f; }
  __syncthreads();
  for (int i = t; i < B_TOK * 2; i += 1024) atomicAdd(&scnt[topk_e[i]], 1);
  float loc[NE];
#pragma unroll
  for (int e = 0; e < NE; e++) loc[e] = 0.f;
  for (int i = t; i < PART_BLOCKS; i += 1024)
#pragma unroll
    for (int e = 0; e < NE; e++) loc[e] += part[i * NE + e];
#pragma unroll
  for (int e = 0; e < NE; e++)
    for (int off = 32; off; off >>= 1) loc[e] += __shfl_xor(loc[e], off);
  if (lane == 0)
#pragma unroll
    for (int e = 0; e < NE; e++) atomicAdd(&ssum[e], loc[e]);
  __syncthreads();
  if (t == 0) {
    float lb = 0.f;
    for (int e = 0; e < NE; e++) {
      float mean = ssum[e] / (float)B_TOK;
      lb += mean * mean;
    }
    *out_lb = lb * (float)NE;
    int off = 0;
    for (int e = 0; e < NE; e++) {
      soff[e] = off;
      off += ((scnt[e] + 255) >> 8) << 8;
    }
    soff[NE] = off;
  }
  __syncthreads();
  if (t <= NE) offsets_pad[t] = soff[t];
  if (t < NE) cursor[t] = soff[t];
  for (int e = 0; e < NE; e++) {
    int s0 = soff[e] + scnt[e], s1 = soff[e + 1];
    for (int i = s0 + t; i < s1; i += 1024) pair_token[i] = 0;
  }
}

// ---------------- scatter: hierarchical (LDS local ranks, 8 global atomics/block) ----------------
__global__ void k_scatter(const int* __restrict__ topk_e, int* __restrict__ cursor,
                          int* __restrict__ pair_token, int* __restrict__ pos_of) {
  __shared__ int lcnt[NE], lbase[NE];
  int t = threadIdx.x;
  if (t < NE) lcnt[t] = 0;
  __syncthreads();
  int b = blockIdx.x * 256 + t;
  int ea = topk_e[b * 2], eb = topk_e[b * 2 + 1];
  int ra = atomicAdd(&lcnt[ea], 1);
  int rb = atomicAdd(&lcnt[eb], 1);
  __syncthreads();
  if (t < NE) lbase[t] = atomicAdd(&cursor[t], lcnt[t]);
  __syncthreads();
  int pa = lbase[ea] + ra, pb = lbase[eb] + rb;
  pair_token[pa] = b;  pos_of[b * 2] = pa;
  pair_token[pb] = b;  pos_of[b * 2 + 1] = pb;
}

// ---------------- transpose+cast W1: [E][DIN][HID] f32 -> [E][HID][DIN] bf16 ----------------
__global__ void k_trans_w1(const float* __restrict__ W1, unsigned short* __restrict__ W1t) {
  __shared__ float tile[64][65];
  int e = blockIdx.z, n0 = blockIdx.x * 64, k0 = blockIdx.y * 64;
  int t = threadIdx.x;
  int r = t >> 4, c4 = (t & 15) * 4;
  const float* src = W1 + ((size_t)e * DIN + k0) * HID + n0;
#pragma unroll
  for (int p = 0; p < 4; p++) {
    int k = r + p * 16;
    float4 v = *(const float4*)&src[(size_t)k * HID + c4];
    tile[k][c4] = v.x; tile[k][c4 + 1] = v.y; tile[k][c4 + 2] = v.z; tile[k][c4 + 3] = v.w;
  }
  __syncthreads();
  int wk = (t & 15) * 4, n = t >> 4;
  unsigned short* dst = W1t + ((size_t)e * HID + n0) * DIN + k0;
#pragma unroll
  for (int p = 0; p < 4; p++) {
    int nn = n + p * 16;
    ushort4 o;
    o.x = f2bf(tile[wk][nn]);     o.y = f2bf(tile[wk + 1][nn]);
    o.z = f2bf(tile[wk + 2][nn]); o.w = f2bf(tile[wk + 3][nn]);
    *(ushort4*)&dst[(size_t)nn * DIN + wk] = o;
  }
}

// ---------------- transpose+cast W2: [E][HID][CLS] f32 -> [E][CPAD][HID] bf16 ----------------
__global__ void k_trans_w2(const float* __restrict__ W2, unsigned short* __restrict__ W2t) {
  __shared__ float tile[64][65];
  int e = blockIdx.z, n0 = blockIdx.x * 64, k0 = blockIdx.y * 64;
  int t = threadIdx.x;
  int r = t >> 4, c4 = (t & 15) * 4;
  const float* src = W2 + ((size_t)e * HID + k0) * CLS + n0;
  if (n0 + 64 <= CLS) {
#pragma unroll
    for (int p = 0; p < 4; p++) {
      int k = r + p * 16;
      float4 v = *(const float4*)&src[(size_t)k * CLS + c4];
      tile[k][c4] = v.x; tile[k][c4 + 1] = v.y; tile[k][c4 + 2] = v.z; tile[k][c4 + 3] = v.w;
    }
  } else {
#pragma unroll
    for (int p = 0; p < 4; p++) {
      int k = r + p * 16;
#pragma unroll
      for (int c = 0; c < 4; c++) {
        int n = n0 + c4 + c;
        tile[k][c4 + c] = (n < CLS) ? src[(size_t)k * CLS + c4 + c] : 0.f;
      }
    }
  }
  __syncthreads();
  int wk = (t & 15) * 4, n = t >> 4;
  unsigned short* dst = W2t + ((size_t)e * CPAD + n0) * HID + k0;
#pragma unroll
  for (int p = 0; p < 4; p++) {
    int nn = n + p * 16;
    ushort4 o;
    o.x = f2bf(tile[wk][nn]);     o.y = f2bf(tile[wk + 1][nn]);
    o.z = f2bf(tile[wk + 2][nn]); o.w = f2bf(tile[wk + 3][nn]);
    *(ushort4*)&dst[(size_t)nn * HID + wk] = o;
  }
}

// ================= 256x256 grouped GEMM, single-barrier K-loop (R10, proven) =================
template<int NT, int A_ROW_BYTES, int B_ROW_BYTES, bool GATHER, int OUT_MODE,
         int BIAS_STRIDE, int OUT_STRIDE, int NCOLS_VALID, int KSPLIT>
__global__ __launch_bounds__(512, 2)
void k_gemm256(const unsigned short* __restrict__ Amat,
               const unsigned short* __restrict__ Bmat,
               const float* __restrict__ bias,
               const int* __restrict__ pair_token,
               const int* __restrict__ offsets_pad,
               void* __restrict__ outp,
               void* __restrict__ outp2,
               size_t b_expert_stride) {
  const int tid = threadIdx.x;
  const int lane = tid & 63;
  const int w = tid >> 6;            // wave 0..7
  const int wm = w >> 2;             // 0..1
  const int wn = w & 3;              // 0..3

  const int nwg = gridDim.x * gridDim.y;
  const int orig = blockIdx.y * gridDim.x + blockIdx.x;
  const int wg = (orig & 7) * (nwg >> 3) + (orig >> 3);
  int bx = wg % gridDim.x;
  const int by = wg / gridDim.x;

  const int p0 = by * 256;
  if (p0 >= offsets_pad[NE]) return;

  int ks = 0;
  if constexpr (KSPLIT == 2) { ks = bx & 1; bx >>= 1; }
  const int n0 = bx * 256;
  const size_t kb = (size_t)ks * NT * 128;   // byte offset into a row

  int e = 0;
#pragma unroll
  for (int i = 1; i < NE; i++) if (p0 >= offsets_pad[i]) e = i;

  __shared__ alignas(16) unsigned short sA[2 * 256 * 64];   // 64 KiB
  __shared__ alignas(16) unsigned short sB[2 * 256 * 64];   // 64 KiB

  const int rl = lane >> 3;                 // 0..7
  const int swz16 = ((lane & 7) ^ rl) << 4; // pre-swizzled 16B slot
  const int frow = lane & 15;
  const int fkb = (lane >> 4) << 4;         // byte offset of k-chunk

  const char* asrc[2][2];
  const char* bsrc[2][2];
  const char* Bexp = (const char*)(Bmat + (size_t)e * b_expert_stride);
#pragma unroll
  for (int h = 0; h < 2; h++)
#pragma unroll
    for (int i = 0; i < 2; i++) {
      int r = h * 128 + w * 16 + i * 8 + rl;
      if constexpr (GATHER) {
        int tk = pair_token[p0 + r];
        asrc[h][i] = (const char*)Amat + (size_t)tk * A_ROW_BYTES + swz16;
      } else {
        asrc[h][i] = (const char*)Amat + (size_t)(p0 + r) * A_ROW_BYTES + swz16;
      }
      bsrc[h][i] = Bexp + (size_t)(n0 + r) * B_ROW_BYTES + swz16;
    }

  floatx4 acc[8][4];
#pragma unroll
  for (int i = 0; i < 8; i++)
#pragma unroll
    for (int j = 0; j < 4; j++) acc[i][j] = (floatx4){0.f, 0.f, 0.f, 0.f};

#define STAGE_A(h, dst, koff)                                            \
  gload16(asrc[h][0] + (koff), (dst) + ((h) * 128 + w * 16 + 0) * 64);   \
  gload16(asrc[h][1] + (koff), (dst) + ((h) * 128 + w * 16 + 8) * 64);
#define STAGE_B(h, dst, koff)                                            \
  gload16(bsrc[h][0] + (koff), (dst) + ((h) * 128 + w * 16 + 0) * 64);   \
  gload16(bsrc[h][1] + (koff), (dst) + ((h) * 128 + w * 16 + 8) * 64);

  // prologue
  STAGE_B(0, sB, kb); STAGE_B(1, sB, kb);
  STAGE_A(0, sA, kb); STAGE_A(1, sA, kb);
  STAGE_B(0, sB + 16384, kb + 128); STAGE_B(1, sB + 16384, kb + 128);
  STAGE_A(0, sA + 16384, kb + 128); STAGE_A(1, sA + 16384, kb + 128);
  VMCNT8();
  BARRIER();

#define RD_A(dst, mh, buf)                                                    \
  _Pragma("unroll") for (int mi = 0; mi < 4; mi++)                            \
  _Pragma("unroll") for (int kk = 0; kk < 2; kk++)                            \
    dst[mi][kk] = ldsrd(buf, wm * 128 + (mh) * 64 + mi * 16 + frow, kk * 64 + fkb);
#define RD_B(dst, nh, buf)                                                    \
  _Pragma("unroll") for (int ni = 0; ni < 2; ni++)                            \
  _Pragma("unroll") for (int kk = 0; kk < 2; kk++)                            \
    dst[ni][kk] = ldsrd(buf, wn * 64 + (nh) * 32 + ni * 16 + frow, kk * 64 + fkb);
#define MFMA_Q(fa, fb, mh, nh)                                                \
  _Pragma("unroll") for (int mi = 0; mi < 4; mi++)                            \
  _Pragma("unroll") for (int ni = 0; ni < 2; ni++)                            \
  _Pragma("unroll") for (int kk = 0; kk < 2; kk++)                            \
    acc[(mh) * 4 + mi][(nh) * 2 + ni] = __builtin_amdgcn_mfma_f32_16x16x32_bf16( \
        fa[mi][kk], fb[ni][kk], acc[(mh) * 4 + mi][(nh) * 2 + ni], 0, 0, 0);

  short8 a[4][2], b0[2][2], b1[2][2];
  RD_A(a, 0, sA); RD_B(b0, 0, sB);

  for (int t = 0; t < NT; ++t) {
    const int cur = t & 1;
    unsigned short* pA = sA + cur * 16384;
    unsigned short* pB = sB + cur * 16384;
    unsigned short* nA = sA + (cur ^ 1) * 16384;
    unsigned short* nB = sB + (cur ^ 1) * 16384;
    const bool s1 = (t + 1 < NT);
    const bool s2 = (t + 2 < NT);
    const size_t off2 = kb + (size_t)(t + 2) * 128;

    MFMA_Q(a, b0, 0, 0);
    RD_B(b1, 1, pB);

    MFMA_Q(a, b1, 0, 1);
    RD_A(a, 1, pA);
    VMCNT0();
    LGKMCNT0();
    BARRIER();

    MFMA_Q(a, b1, 1, 1);
    if (s2) { STAGE_B(0, pB, off2); STAGE_B(1, pB, off2); }

    MFMA_Q(a, b0, 1, 0);
    if (s1) { RD_B(b0, 0, nB); RD_A(a, 0, nA); }
    if (s2) { STAGE_A(0, pA, off2); STAGE_A(1, pA, off2); }
  }
#undef RD_A
#undef RD_B
#undef MFMA_Q
#undef STAGE_A
#undef STAGE_B

  // epilogue (bf16 out both modes)
  const int cl = lane & 15;
  const int rj = (lane >> 4) * 4;
  const int ocol0 = n0 + wn * 64;
  const int orow0 = p0 + wm * 128;
  unsigned short* out = (unsigned short*)outp;
  if constexpr (KSPLIT == 2) { if (ks) out = (unsigned short*)outp2; }
#pragma unroll
  for (int ni = 0; ni < 4; ni++) {
    int col = ocol0 + ni * 16 + cl;
    float bv = (ks == 0 && col < NCOLS_VALID) ? bias[e * BIAS_STRIDE + col] : 0.f;
#pragma unroll
    for (int mi = 0; mi < 8; mi++) {
      size_t rbase = (size_t)(orow0 + mi * 16 + rj) * OUT_STRIDE + col;
#pragma unroll
      for (int j = 0; j < 4; j++) {
        float v = acc[mi][ni][j] + bv;
        if constexpr (OUT_MODE == 0) v = fmaxf(v, 0.f);
        out[rbase + (size_t)j * OUT_STRIDE] = f2bf(v);
      }
    }
  }
}

// ================= DIAGNOSTIC ablation clones (scratch output, grid 16x16) =================
// MODE bit0 = in-loop staging+vmcnt0, bit1 = in-loop ds_reads.
// 3=full, 2=reads-only (no staging), 1=staging-only (no reads), 0=MFMA+sync floor.
// Deterministic: LDS contents are a pure function of staged inputs.
template<int MODE>
__global__ __launch_bounds__(512, 2)
void k_diag(const unsigned short* __restrict__ Amat,
            const unsigned short* __restrict__ Bmat,
            const int* __restrict__ pair_token,
            const int* __restrict__ offsets_pad,
            float* __restrict__ scratch) {
  constexpr int NT = DIN / 64;
  constexpr bool DO_STAGE = (MODE & 1);
  constexpr bool DO_READ  = (MODE & 2);
  const int tid = threadIdx.x;
  const int lane = tid & 63;
  const int w = tid >> 6;
  const int wm = w >> 2;
  const int wn = w & 3;
  const int p0 = blockIdx.y * 256;
  const int n0 = blockIdx.x * 256;
  int e = 0;
#pragma unroll
  for (int i = 1; i < NE; i++) if (p0 >= offsets_pad[i]) e = i;

  __shared__ alignas(16) unsigned short sA[2 * 256 * 64];
  __shared__ alignas(16) unsigned short sB[2 * 256 * 64];

  const int rl = lane >> 3;
  const int swz16 = ((lane & 7) ^ rl) << 4;
  const int frow = lane & 15;
  const int fkb = (lane >> 4) << 4;

  const char* asrc[2][2];
  const char* bsrc[2][2];
  const char* Bexp = (const char*)(Bmat + (size_t)e * HID * DIN);
#pragma unroll
  for (int h = 0; h < 2; h++)
#pragma unroll
    for (int i = 0; i < 2; i++) {
      int r = h * 128 + w * 16 + i * 8 + rl;
      int tk = pair_token[p0 + r];
      asrc[h][i] = (const char*)Amat + (size_t)tk * (DIN * 2) + swz16;
      bsrc[h][i] = Bexp + (size_t)(n0 + r) * (DIN * 2) + swz16;
    }

  floatx4 acc[8][4];
#pragma unroll
  for (int i = 0; i < 8; i++)
#pragma unroll
    for (int j = 0; j < 4; j++) acc[i][j] = (floatx4){0.f, 0.f, 0.f, 0.f};

#define D_STAGE_A(h, dst, koff)                                          \
  gload16(asrc[h][0] + (koff), (dst) + ((h) * 128 + w * 16 + 0) * 64);   \
  gload16(asrc[h][1] + (koff), (dst) + ((h) * 128 + w * 16 + 8) * 64);
#define D_STAGE_B(h, dst, koff)                                          \
  gload16(bsrc[h][0] + (koff), (dst) + ((h) * 128 + w * 16 + 0) * 64);   \
  gload16(bsrc[h][1] + (koff), (dst) + ((h) * 128 + w * 16 + 8) * 64);
#define D_RD_A(dst, mh, buf)                                                  \
  _Pragma("unroll") for (int mi = 0; mi < 4; mi++)                            \
  _Pragma("unroll") for (int kk = 0; kk < 2; kk++)                            \
    dst[mi][kk] = ldsrd(buf, wm * 128 + (mh) * 64 + mi * 16 + frow, kk * 64 + fkb);
#define D_RD_B(dst, nh, buf)                                                  \
  _Pragma("unroll") for (int ni = 0; ni < 2; ni++)                            \
  _Pragma("unroll") for (int kk = 0; kk < 2; kk++)                            \
    dst[ni][kk] = ldsrd(buf, wn * 64 + (nh) * 32 + ni * 16 + frow, kk * 64 + fkb);
#define D_MFMA_Q(fa, fb, mh, nh)                                              \
  _Pragma("unroll") for (int mi = 0; mi < 4; mi++)                            \
  _Pragma("unroll") for (int ni = 0; ni < 2; ni++)                            \
  _Pragma("unroll") for (int kk = 0; kk < 2; kk++)                            \
    acc[(mh) * 4 + mi][(nh) * 2 + ni] = __builtin_amdgcn_mfma_f32_16x16x32_bf16( \
        fa[mi][kk], fb[ni][kk], acc[(mh) * 4 + mi][(nh) * 2 + ni], 0, 0, 0);

  // prologue (all modes): stage tiles 0,1
  D_STAGE_B(0, sB, 0); D_STAGE_B(1, sB, 0);
  D_STAGE_A(0, sA, 0); D_STAGE_A(1, sA, 0);
  D_STAGE_B(0, sB + 16384, 128); D_STAGE_B(1, sB + 16384, 128);
  D_STAGE_A(0, sA + 16384, 128); D_STAGE_A(1, sA + 16384, 128);
  VMCNT8();
  BARRIER();

  short8 a[4][2], b0[2][2], b1[2][2];
  D_RD_A(a, 0, sA); D_RD_B(b0, 0, sB);
  D_RD_B(b1, 1, sB);          // pre-init b1 for no-read modes
  LGKMCNT0();

  for (int t = 0; t < NT; ++t) {
    const int cur = t & 1;
    unsigned short* pA = sA + cur * 16384;
    unsigned short* pB = sB + cur * 16384;
    unsigned short* nA = sA + (cur ^ 1) * 16384;
    unsigned short* nB = sB + (cur ^ 1) * 16384;
    const bool s1 = (t + 1 < NT);
    const bool s2 = (t + 2 < NT);
    const size_t off2 = (size_t)(t + 2) * 128;

    D_MFMA_Q(a, b0, 0, 0);
    if (DO_READ) { D_RD_B(b1, 1, pB); }

    D_MFMA_Q(a, b1, 0, 1);
    if (DO_READ) { D_RD_A(a, 1, pA); }
    if (DO_STAGE) { VMCNT0(); }
    LGKMCNT0();
    BARRIER();

    D_MFMA_Q(a, b1, 1, 1);
    if (DO_STAGE && s2) { D_STAGE_B(0, pB, off2); D_STAGE_B(1, pB, off2); }

    D_MFMA_Q(a, b0, 1, 0);
    if (DO_READ && s1) { D_RD_B(b0, 0, nB); D_RD_A(a, 0, nA); }
    if (DO_STAGE && s2) { D_STAGE_A(0, pA, off2); D_STAGE_A(1, pA, off2); }
  }
#undef D_RD_A
#undef D_RD_B
#undef D_MFMA_Q
#undef D_STAGE_A
#undef D_STAGE_B

  // keep everything live: reduce acc to one float per thread
  float s = 0.f;
#pragma unroll
  for (int i = 0; i < 8; i++)
#pragma unroll
    for (int j = 0; j < 4; j++)
#pragma unroll
      for (int q = 0; q < 4; q++) s += acc[i][j][q];
  scratch[(size_t)(blockIdx.y * gridDim.x + blockIdx.x) * 512 + tid] = s;
}

// ---------------- combine (bf16 partials) ----------------
__global__ void k_combine(const unsigned short* __restrict__ yA,
                          const unsigned short* __restrict__ yB,
                          const int* __restrict__ pos_of, const float* __restrict__ topk_w,
                          float* __restrict__ out) {
  int b = blockIdx.x, t = threadIdx.x;
  if (t >= 250) return;   // 250 x 4 = 1000 cols
  int q0 = pos_of[b * 2], q1 = pos_of[b * 2 + 1];
  float w0 = topk_w[b * 2], w1 = topk_w[b * 2 + 1];
  const ushort4 a0 = *(const ushort4*)(yA + (size_t)q0 * CPAD + t * 4);
  const ushort4 c0 = *(const ushort4*)(yB + (size_t)q0 * CPAD + t * 4);
  const ushort4 a1 = *(const ushort4*)(yA + (size_t)q1 * CPAD + t * 4);
  const ushort4 c1 = *(const ushort4*)(yB + (size_t)q1 * CPAD + t * 4);
  float4 r;
  r.x = w0 * (bf2f(a0.x) + bf2f(c0.x)) + w1 * (bf2f(a1.x) + bf2f(c1.x));
  r.y = w0 * (bf2f(a0.y) + bf2f(c0.y)) + w1 * (bf2f(a1.y) + bf2f(c1.y));
  r.z = w0 * (bf2f(a0.z) + bf2f(c0.z)) + w1 * (bf2f(a1.z) + bf2f(c1.z));
  r.w = w0 * (bf2f(a0.w) + bf2f(c0.w)) + w1 * (bf2f(a1.w) + bf2f(c1.w));
  ((float4*)(out + (size_t)b * CLS))[t] = r;
}

__global__ void k_sentinel(float* out) { if (threadIdx.x == 0) out[0] = 1.0e9f; }

extern "C" void kernel_launch(void* const* d_in, const int* in_sizes, int n_in,
                              void* d_out, int out_size, void* d_ws, size_t ws_size,
                              hipStream_t stream) {
  const float* x  = (const float*)d_in[0];
  const float* Wg = (const float*)d_in[1];
  const float* bg = (const float*)d_in[2];
  const float* W1 = (const float*)d_in[3];
  const float* b1 = (const float*)d_in[4];
  const float* W2 = (const float*)d_in[5];
  const float* b2 = (const float*)d_in[6];
  float* out = (float*)d_out;

  char* w = (char*)d_ws;
  int* offsets_pad = (int*)w;  w += 256;
  int* cursor = (int*)w;       w += 256;
  float* part = (float*)w;     w += (size_t)PART_BLOCKS * NE * 4;
  int* topk_e = (int*)w;       w += (size_t)B_TOK * 2 * 4;
  float* topk_w = (float*)w;   w += (size_t)B_TOK * 2 * 4;
  int* pos_of = (int*)w;       w += (size_t)B_TOK * 2 * 4;
  int* pair_token = (int*)w;   w += (size_t)PAIR_CAP * 4;
  char* big = w;
  unsigned short* xb  = (unsigned short*)big;
  unsigned short* W1t = (unsigned short*)(big + (size_t)B_TOK * DIN * 2);
  unsigned short* W2t = (unsigned short*)((char*)W1t + (size_t)NE * HID * DIN * 2);
  unsigned short* hbuf = (unsigned short*)((char*)W2t + (size_t)NE * CPAD * HID * 2);
  unsigned short* ybufB = (unsigned short*)((char*)hbuf + (size_t)PAIR_CAP * HID * 2);
  float* diag = (float*)((char*)ybufB + (size_t)PAIR_CAP * CPAD * 2);
  unsigned short* ybufA = (unsigned short*)big;   // aliases xb+W1t (dead by GEMM2)
  size_t need = (size_t)(((char*)diag + (size_t)256 * 512 * 4) - (char*)d_ws);
  if (ws_size < need) {
    k_sentinel<<<1, 64, 0, stream>>>(out);
    return;
  }

  k_gate<<<PART_BLOCKS, 256, 0, stream>>>(x, Wg, bg, part, topk_e, topk_w,
                                          (ushort4*)xb);
  k_setup<<<1, 1024, 0, stream>>>(topk_e, offsets_pad, cursor, part, pair_token,
                                  out + (size_t)B_TOK * CLS);
  k_scatter<<<B_TOK / 256, 256, 0, stream>>>(topk_e, cursor, pair_token, pos_of);

  k_trans_w1<<<dim3(HID / 64, DIN / 64, NE), 256, 0, stream>>>(W1, W1t);
  k_trans_w2<<<dim3(CPAD / 64, HID / 64, NE), 256, 0, stream>>>(W2, W2t);

  // GEMM1: h = relu(xb[gather] @ W1t^T + b1)
  k_gemm256<DIN / 64, DIN * 2, DIN * 2, true, 0, HID, HID, HID, 1>
      <<<dim3(HID / 256, PAIR_CAP / 256), 512, 0, stream>>>(
          xb, W1t, b1, pair_token, offsets_pad, hbuf, nullptr, (size_t)HID * DIN);

  // GEMM2: y = hbuf @ W2t^T + b2 (bf16 partials), K-split x2
  k_gemm256<HID / 128, HID * 2, HID * 2, false, 1, CLS, CPAD, CLS, 2>
      <<<dim3((CPAD / 256) * 2, PAIR_CAP / 256), 512, 0, stream>>>(
          hbuf, W2t, b2, pair_token, offsets_pad, ybufA, ybufB, (size_t)CPAD * HID);

  k_combine<<<B_TOK, 256, 0, stream>>>(ybufA, ybufB, pos_of, topk_w, out);

  // -------- diagnostics (scratch-only, grid 256): ablate the K-loop --------
  k_diag<3><<<dim3(16, 16), 512, 0, stream>>>(xb, W1t, pair_token, offsets_pad, diag);
  k_diag<2><<<dim3(16, 16), 512, 0, stream>>>(xb, W1t, pair_token, offsets_pad, diag);
  k_diag<1><<<dim3(16, 16), 512, 0, stream>>>(xb, W1t, pair_token, offsets_pad, diag);
  k_diag<0><<<dim3(16, 16), 512, 0, stream>>>(xb, W1t, pair_token, offsets_pad, diag);
}

// Round 12
// 530.845 us; speedup vs baseline: 1.1257x; 1.1257x over previous
//
#include <hip/hip_runtime.h>
#include <hip/hip_bf16.h>
#include <cstdint>

#define B_TOK 8192
#define DIN   1024
#define HID   4096
#define CLS   1000
#define CPAD  1024
#define NE    8
#define PAIR_CAP 18432           // 16384 + 8*256, multiple of 256
#define PART_BLOCKS 2048

typedef __attribute__((ext_vector_type(8))) short short8;
typedef __attribute__((ext_vector_type(4))) float floatx4;

__device__ __forceinline__ unsigned short f2bf(float f) {
  unsigned int u = __builtin_bit_cast(unsigned int, f);
  u += 0x7fffu + ((u >> 16) & 1u);   // RNE
  return (unsigned short)(u >> 16);
}

__device__ __forceinline__ float bf2f(unsigned short u) {
  return __builtin_bit_cast(float, (unsigned int)u << 16);
}

__device__ __forceinline__ void gload16(const void* g, void* l) {
  __builtin_amdgcn_global_load_lds(
      (const __attribute__((address_space(1))) void*)(uintptr_t)g,
      (__attribute__((address_space(3))) void*)(unsigned int)(uintptr_t)l,
      16, 0, 0);
}

#define BARRIER()  asm volatile("s_barrier" ::: "memory")
#define VMCNT8()   asm volatile("s_waitcnt vmcnt(8)" ::: "memory")
#define VMCNT0()   asm volatile("s_waitcnt vmcnt(0)" ::: "memory")
#define LGKMCNT0() asm volatile("s_waitcnt lgkmcnt(0)" ::: "memory")

// swizzled LDS read: 16B at (row, byte-in-row), XOR-swizzle on 16B slot
__device__ __forceinline__ short8 ldsrd(const unsigned short* buf, int row, int bir) {
  const char* p = (const char*)buf + row * 128 + (bir ^ ((row & 7) << 4));
  return *(const short8*)p;
}

// ---------------- gating: one wave per token (fused x -> bf16 cast; NO global atomics) ----------------
__global__ void k_gate(const float* __restrict__ x, const float* __restrict__ Wg,
                       const float* __restrict__ bg,
                       float* __restrict__ part, int* __restrict__ topk_e,
                       float* __restrict__ topk_w, ushort4* __restrict__ xb4) {
  int tok = (blockIdx.x * blockDim.x + threadIdx.x) >> 6;
  int lane = threadIdx.x & 63;
  __shared__ float psum[NE];
  if (threadIdx.x < NE) psum[threadIdx.x] = 0.f;
  __syncthreads();

  float acc[NE];
#pragma unroll
  for (int e = 0; e < NE; e++) acc[e] = 0.f;
  const float4* xr4 = (const float4*)(x + (size_t)tok * DIN);
#pragma unroll
  for (int i = 0; i < 4; i++) {
    int d4 = lane + i * 64;
    float4 v = xr4[d4];
    ushort4 o;
    o.x = f2bf(v.x); o.y = f2bf(v.y); o.z = f2bf(v.z); o.w = f2bf(v.w);
    xb4[(size_t)tok * (DIN / 4) + d4] = o;
    float vs[4] = {v.x, v.y, v.z, v.w};
#pragma unroll
    for (int c = 0; c < 4; c++) {
      const float4* wr4 = (const float4*)(Wg + (size_t)(d4 * 4 + c) * NE);
      float4 wa = wr4[0], wb = wr4[1];
      float xv = vs[c];
      acc[0] += xv * wa.x; acc[1] += xv * wa.y; acc[2] += xv * wa.z; acc[3] += xv * wa.w;
      acc[4] += xv * wb.x; acc[5] += xv * wb.y; acc[6] += xv * wb.z; acc[7] += xv * wb.w;
    }
  }
#pragma unroll
  for (int e = 0; e < NE; e++)
    for (int off = 32; off; off >>= 1) acc[e] += __shfl_xor(acc[e], off);

  if (lane == 0) {
    float p[NE];
    float m = -1e30f;
#pragma unroll
    for (int e = 0; e < NE; e++) { p[e] = acc[e] + bg[e]; m = fmaxf(m, p[e]); }
    float s = 0.f;
#pragma unroll
    for (int e = 0; e < NE; e++) { p[e] = expf(p[e] - m); s += p[e]; }
    float inv = 1.f / s;
#pragma unroll
    for (int e = 0; e < NE; e++) p[e] *= inv;
    int e0 = 0;
#pragma unroll
    for (int e = 1; e < NE; e++) if (p[e] > p[e0]) e0 = e;
    int e1 = -1;
#pragma unroll
    for (int e = 0; e < NE; e++) {
      if (e == e0) continue;
      if (e1 < 0 || p[e] > p[e1]) e1 = e;
    }
    float wi = 1.f / (p[e0] + p[e1]);
    topk_e[tok * 2] = e0;  topk_e[tok * 2 + 1] = e1;
    topk_w[tok * 2] = p[e0] * wi;  topk_w[tok * 2 + 1] = p[e1] * wi;
#pragma unroll
    for (int e = 0; e < NE; e++) atomicAdd(&psum[e], p[e]);   // LDS only
  }
  __syncthreads();
  if (threadIdx.x < NE) part[blockIdx.x * NE + threadIdx.x] = psum[threadIdx.x];
}

// ---------------- setup: histogram counts, offsets (256-pad), cursors, lb_loss, dummy fill ----------------
__global__ void k_setup(const int* __restrict__ topk_e, int* __restrict__ offsets_pad,
                        int* __restrict__ cursor, const float* __restrict__ part,
                        int* __restrict__ pair_token, float* __restrict__ out_lb) {
  __shared__ int scnt[NE];
  __shared__ int soff[NE + 1];
  __shared__ float ssum[NE];
  int t = threadIdx.x;            // 1024 threads
  int lane = t & 63;
  if (t < NE) { scnt[t] = 0; ssum[t] = 0.f; }
  __syncthreads();
  for (int i = t; i < B_TOK * 2; i += 1024) atomicAdd(&scnt[topk_e[i]], 1);
  float loc[NE];
#pragma unroll
  for (int e = 0; e < NE; e++) loc[e] = 0.f;
  for (int i = t; i < PART_BLOCKS; i += 1024)
#pragma unroll
    for (int e = 0; e < NE; e++) loc[e] += part[i * NE + e];
#pragma unroll
  for (int e = 0; e < NE; e++)
    for (int off = 32; off; off >>= 1) loc[e] += __shfl_xor(loc[e], off);
  if (lane == 0)
#pragma unroll
    for (int e = 0; e < NE; e++) atomicAdd(&ssum[e], loc[e]);
  __syncthreads();
  if (t == 0) {
    float lb = 0.f;
    for (int e = 0; e < NE; e++) {
      float mean = ssum[e] / (float)B_TOK;
      lb += mean * mean;
    }
    *out_lb = lb * (float)NE;
    int off = 0;
    for (int e = 0; e < NE; e++) {
      soff[e] = off;
      off += ((scnt[e] + 255) >> 8) << 8;
    }
    soff[NE] = off;
  }
  __syncthreads();
  if (t <= NE) offsets_pad[t] = soff[t];
  if (t < NE) cursor[t] = soff[t];
  for (int e = 0; e < NE; e++) {
    int s0 = soff[e] + scnt[e], s1 = soff[e + 1];
    for (int i = s0 + t; i < s1; i += 1024) pair_token[i] = 0;
  }
}

// ---------------- scatter: hierarchical (LDS local ranks, 8 global atomics/block) ----------------
__global__ void k_scatter(const int* __restrict__ topk_e, int* __restrict__ cursor,
                          int* __restrict__ pair_token, int* __restrict__ pos_of) {
  __shared__ int lcnt[NE], lbase[NE];
  int t = threadIdx.x;
  if (t < NE) lcnt[t] = 0;
  __syncthreads();
  int b = blockIdx.x * 256 + t;
  int ea = topk_e[b * 2], eb = topk_e[b * 2 + 1];
  int ra = atomicAdd(&lcnt[ea], 1);
  int rb = atomicAdd(&lcnt[eb], 1);
  __syncthreads();
  if (t < NE) lbase[t] = atomicAdd(&cursor[t], lcnt[t]);
  __syncthreads();
  int pa = lbase[ea] + ra, pb = lbase[eb] + rb;
  pair_token[pa] = b;  pos_of[b * 2] = pa;
  pair_token[pb] = b;  pos_of[b * 2 + 1] = pb;
}

// ---------------- transpose+cast W1: [E][DIN][HID] f32 -> [E][HID][DIN] bf16 ----------------
__global__ void k_trans_w1(const float* __restrict__ W1, unsigned short* __restrict__ W1t) {
  __shared__ float tile[64][65];
  int e = blockIdx.z, n0 = blockIdx.x * 64, k0 = blockIdx.y * 64;
  int t = threadIdx.x;
  int r = t >> 4, c4 = (t & 15) * 4;
  const float* src = W1 + ((size_t)e * DIN + k0) * HID + n0;
#pragma unroll
  for (int p = 0; p < 4; p++) {
    int k = r + p * 16;
    float4 v = *(const float4*)&src[(size_t)k * HID + c4];
    tile[k][c4] = v.x; tile[k][c4 + 1] = v.y; tile[k][c4 + 2] = v.z; tile[k][c4 + 3] = v.w;
  }
  __syncthreads();
  int wk = (t & 15) * 4, n = t >> 4;
  unsigned short* dst = W1t + ((size_t)e * HID + n0) * DIN + k0;
#pragma unroll
  for (int p = 0; p < 4; p++) {
    int nn = n + p * 16;
    ushort4 o;
    o.x = f2bf(tile[wk][nn]);     o.y = f2bf(tile[wk + 1][nn]);
    o.z = f2bf(tile[wk + 2][nn]); o.w = f2bf(tile[wk + 3][nn]);
    *(ushort4*)&dst[(size_t)nn * DIN + wk] = o;
  }
}

// ---------------- transpose+cast W2: [E][HID][CLS] f32 -> [E][CPAD][HID] bf16 ----------------
__global__ void k_trans_w2(const float* __restrict__ W2, unsigned short* __restrict__ W2t) {
  __shared__ float tile[64][65];
  int e = blockIdx.z, n0 = blockIdx.x * 64, k0 = blockIdx.y * 64;
  int t = threadIdx.x;
  int r = t >> 4, c4 = (t & 15) * 4;
  const float* src = W2 + ((size_t)e * HID + k0) * CLS + n0;
  if (n0 + 64 <= CLS) {
#pragma unroll
    for (int p = 0; p < 4; p++) {
      int k = r + p * 16;
      float4 v = *(const float4*)&src[(size_t)k * CLS + c4];
      tile[k][c4] = v.x; tile[k][c4 + 1] = v.y; tile[k][c4 + 2] = v.z; tile[k][c4 + 3] = v.w;
    }
  } else {
#pragma unroll
    for (int p = 0; p < 4; p++) {
      int k = r + p * 16;
#pragma unroll
      for (int c = 0; c < 4; c++) {
        int n = n0 + c4 + c;
        tile[k][c4 + c] = (n < CLS) ? src[(size_t)k * CLS + c4 + c] : 0.f;
      }
    }
  }
  __syncthreads();
  int wk = (t & 15) * 4, n = t >> 4;
  unsigned short* dst = W2t + ((size_t)e * CPAD + n0) * HID + k0;
#pragma unroll
  for (int p = 0; p < 4; p++) {
    int nn = n + p * 16;
    ushort4 o;
    o.x = f2bf(tile[wk][nn]);     o.y = f2bf(tile[wk + 1][nn]);
    o.z = f2bf(tile[wk + 2][nn]); o.w = f2bf(tile[wk + 3][nn]);
    *(ushort4*)&dst[(size_t)nn * HID + wk] = o;
  }
}

// ================= 256x256 grouped GEMM, single-barrier K-loop (R10, proven) =================
// KSPLIT=4: ks = bx%4; partial ks -> (ks<2 ? outp : outp2) + (ks&1)*PAIR_CAP*OUT_STRIDE.
template<int NT, int A_ROW_BYTES, int B_ROW_BYTES, bool GATHER, int OUT_MODE,
         int BIAS_STRIDE, int OUT_STRIDE, int NCOLS_VALID, int KSPLIT>
__global__ __launch_bounds__(512, 2)
void k_gemm256(const unsigned short* __restrict__ Amat,
               const unsigned short* __restrict__ Bmat,
               const float* __restrict__ bias,
               const int* __restrict__ pair_token,
               const int* __restrict__ offsets_pad,
               void* __restrict__ outp,
               void* __restrict__ outp2,
               size_t b_expert_stride) {
  const int tid = threadIdx.x;
  const int lane = tid & 63;
  const int w = tid >> 6;            // wave 0..7
  const int wm = w >> 2;             // 0..1
  const int wn = w & 3;              // 0..3

  const int nwg = gridDim.x * gridDim.y;
  const int orig = blockIdx.y * gridDim.x + blockIdx.x;
  const int wg = (orig & 7) * (nwg >> 3) + (orig >> 3);
  int bx = wg % gridDim.x;
  const int by = wg / gridDim.x;

  const int p0 = by * 256;
  if (p0 >= offsets_pad[NE]) return;

  int ks = 0;
  if constexpr (KSPLIT > 1) { ks = bx % KSPLIT; bx /= KSPLIT; }
  const int n0 = bx * 256;
  const size_t kb = (size_t)ks * NT * 128;   // byte offset into a row

  int e = 0;
#pragma unroll
  for (int i = 1; i < NE; i++) if (p0 >= offsets_pad[i]) e = i;

  __shared__ alignas(16) unsigned short sA[2 * 256 * 64];   // 64 KiB
  __shared__ alignas(16) unsigned short sB[2 * 256 * 64];   // 64 KiB

  const int rl = lane >> 3;                 // 0..7
  const int swz16 = ((lane & 7) ^ rl) << 4; // pre-swizzled 16B slot
  const int frow = lane & 15;
  const int fkb = (lane >> 4) << 4;         // byte offset of k-chunk

  const char* asrc[2][2];
  const char* bsrc[2][2];
  const char* Bexp = (const char*)(Bmat + (size_t)e * b_expert_stride);
#pragma unroll
  for (int h = 0; h < 2; h++)
#pragma unroll
    for (int i = 0; i < 2; i++) {
      int r = h * 128 + w * 16 + i * 8 + rl;
      if constexpr (GATHER) {
        int tk = pair_token[p0 + r];
        asrc[h][i] = (const char*)Amat + (size_t)tk * A_ROW_BYTES + swz16;
      } else {
        asrc[h][i] = (const char*)Amat + (size_t)(p0 + r) * A_ROW_BYTES + swz16;
      }
      bsrc[h][i] = Bexp + (size_t)(n0 + r) * B_ROW_BYTES + swz16;
    }

  floatx4 acc[8][4];
#pragma unroll
  for (int i = 0; i < 8; i++)
#pragma unroll
    for (int j = 0; j < 4; j++) acc[i][j] = (floatx4){0.f, 0.f, 0.f, 0.f};

#define STAGE_A(h, dst, koff)                                            \
  gload16(asrc[h][0] + (koff), (dst) + ((h) * 128 + w * 16 + 0) * 64);   \
  gload16(asrc[h][1] + (koff), (dst) + ((h) * 128 + w * 16 + 8) * 64);
#define STAGE_B(h, dst, koff)                                            \
  gload16(bsrc[h][0] + (koff), (dst) + ((h) * 128 + w * 16 + 0) * 64);   \
  gload16(bsrc[h][1] + (koff), (dst) + ((h) * 128 + w * 16 + 8) * 64);

  // prologue
  STAGE_B(0, sB, kb); STAGE_B(1, sB, kb);
  STAGE_A(0, sA, kb); STAGE_A(1, sA, kb);
  STAGE_B(0, sB + 16384, kb + 128); STAGE_B(1, sB + 16384, kb + 128);
  STAGE_A(0, sA + 16384, kb + 128); STAGE_A(1, sA + 16384, kb + 128);
  VMCNT8();
  BARRIER();

#define RD_A(dst, mh, buf)                                                    \
  _Pragma("unroll") for (int mi = 0; mi < 4; mi++)                            \
  _Pragma("unroll") for (int kk = 0; kk < 2; kk++)                            \
    dst[mi][kk] = ldsrd(buf, wm * 128 + (mh) * 64 + mi * 16 + frow, kk * 64 + fkb);
#define RD_B(dst, nh, buf)                                                    \
  _Pragma("unroll") for (int ni = 0; ni < 2; ni++)                            \
  _Pragma("unroll") for (int kk = 0; kk < 2; kk++)                            \
    dst[ni][kk] = ldsrd(buf, wn * 64 + (nh) * 32 + ni * 16 + frow, kk * 64 + fkb);
#define MFMA_Q(fa, fb, mh, nh)                                                \
  _Pragma("unroll") for (int mi = 0; mi < 4; mi++)                            \
  _Pragma("unroll") for (int ni = 0; ni < 2; ni++)                            \
  _Pragma("unroll") for (int kk = 0; kk < 2; kk++)                            \
    acc[(mh) * 4 + mi][(nh) * 2 + ni] = __builtin_amdgcn_mfma_f32_16x16x32_bf16( \
        fa[mi][kk], fb[ni][kk], acc[(mh) * 4 + mi][(nh) * 2 + ni], 0, 0, 0);

  short8 a[4][2], b0[2][2], b1[2][2];
  RD_A(a, 0, sA); RD_B(b0, 0, sB);

  for (int t = 0; t < NT; ++t) {
    const int cur = t & 1;
    unsigned short* pA = sA + cur * 16384;
    unsigned short* pB = sB + cur * 16384;
    unsigned short* nA = sA + (cur ^ 1) * 16384;
    unsigned short* nB = sB + (cur ^ 1) * 16384;
    const bool s1 = (t + 1 < NT);
    const bool s2 = (t + 2 < NT);
    const size_t off2 = kb + (size_t)(t + 2) * 128;

    MFMA_Q(a, b0, 0, 0);
    RD_B(b1, 1, pB);

    MFMA_Q(a, b1, 0, 1);
    RD_A(a, 1, pA);
    VMCNT0();
    LGKMCNT0();
    BARRIER();

    MFMA_Q(a, b1, 1, 1);
    if (s2) { STAGE_B(0, pB, off2); STAGE_B(1, pB, off2); }

    MFMA_Q(a, b0, 1, 0);
    if (s1) { RD_B(b0, 0, nB); RD_A(a, 0, nA); }
    if (s2) { STAGE_A(0, pA, off2); STAGE_A(1, pA, off2); }
  }
#undef RD_A
#undef RD_B
#undef MFMA_Q
#undef STAGE_A
#undef STAGE_B

  // epilogue (bf16 out both modes)
  const int cl = lane & 15;
  const int rj = (lane >> 4) * 4;
  const int ocol0 = n0 + wn * 64;
  const int orow0 = p0 + wm * 128;
  unsigned short* out = (unsigned short*)outp;
  if constexpr (KSPLIT == 4) {
    out = (unsigned short*)(ks < 2 ? outp : outp2);
    if (ks & 1) out += (size_t)PAIR_CAP * OUT_STRIDE;
  }
#pragma unroll
  for (int ni = 0; ni < 4; ni++) {
    int col = ocol0 + ni * 16 + cl;
    float bv = (ks == 0 && col < NCOLS_VALID) ? bias[e * BIAS_STRIDE + col] : 0.f;
#pragma unroll
    for (int mi = 0; mi < 8; mi++) {
      size_t rbase = (size_t)(orow0 + mi * 16 + rj) * OUT_STRIDE + col;
#pragma unroll
      for (int j = 0; j < 4; j++) {
        float v = acc[mi][ni][j] + bv;
        if constexpr (OUT_MODE == 0) v = fmaxf(v, 0.f);
        out[rbase + (size_t)j * OUT_STRIDE] = f2bf(v);
      }
    }
  }
}

// ---------------- combine (4 bf16 partial buffers) ----------------
// partial ks layout: yF + 0, yF + PC*CPAD, yB + 0, yB + PC*CPAD
__global__ void k_combine(const unsigned short* __restrict__ yF,
                          const unsigned short* __restrict__ yB_,
                          const int* __restrict__ pos_of, const float* __restrict__ topk_w,
                          float* __restrict__ out) {
  int b = blockIdx.x, t = threadIdx.x;
  if (t >= 250) return;   // 250 x 4 = 1000 cols
  int q0 = pos_of[b * 2], q1 = pos_of[b * 2 + 1];
  float w0 = topk_w[b * 2], w1 = topk_w[b * 2 + 1];
  const size_t S = (size_t)PAIR_CAP * CPAD;
  float4 r = {0.f, 0.f, 0.f, 0.f};
#pragma unroll
  for (int q = 0; q < 2; q++) {
    size_t pos = (size_t)(q == 0 ? q0 : q1) * CPAD + t * 4;
    float wq = q == 0 ? w0 : w1;
    const ushort4 p0 = *(const ushort4*)(yF + pos);
    const ushort4 p1 = *(const ushort4*)(yF + S + pos);
    const ushort4 p2 = *(const ushort4*)(yB_ + pos);
    const ushort4 p3 = *(const ushort4*)(yB_ + S + pos);
    r.x += wq * (bf2f(p0.x) + bf2f(p1.x) + bf2f(p2.x) + bf2f(p3.x));
    r.y += wq * (bf2f(p0.y) + bf2f(p1.y) + bf2f(p2.y) + bf2f(p3.y));
    r.z += wq * (bf2f(p0.z) + bf2f(p1.z) + bf2f(p2.z) + bf2f(p3.z));
    r.w += wq * (bf2f(p0.w) + bf2f(p1.w) + bf2f(p2.w) + bf2f(p3.w));
  }
  ((float4*)(out + (size_t)b * CLS))[t] = r;
}

__global__ void k_sentinel(float* out) { if (threadIdx.x == 0) out[0] = 1.0e9f; }

extern "C" void kernel_launch(void* const* d_in, const int* in_sizes, int n_in,
                              void* d_out, int out_size, void* d_ws, size_t ws_size,
                              hipStream_t stream) {
  const float* x  = (const float*)d_in[0];
  const float* Wg = (const float*)d_in[1];
  const float* bg = (const float*)d_in[2];
  const float* W1 = (const float*)d_in[3];
  const float* b1 = (const float*)d_in[4];
  const float* W2 = (const float*)d_in[5];
  const float* b2 = (const float*)d_in[6];
  float* out = (float*)d_out;

  char* w = (char*)d_ws;
  int* offsets_pad = (int*)w;  w += 256;
  int* cursor = (int*)w;       w += 256;
  float* part = (float*)w;     w += (size_t)PART_BLOCKS * NE * 4;
  int* topk_e = (int*)w;       w += (size_t)B_TOK * 2 * 4;
  float* topk_w = (float*)w;   w += (size_t)B_TOK * 2 * 4;
  int* pos_of = (int*)w;       w += (size_t)B_TOK * 2 * 4;
  int* pair_token = (int*)w;   w += (size_t)PAIR_CAP * 4;
  char* big = w;
  unsigned short* xb  = (unsigned short*)big;
  unsigned short* W1t = (unsigned short*)(big + (size_t)B_TOK * DIN * 2);
  unsigned short* W2t = (unsigned short*)((char*)W1t + (size_t)NE * HID * DIN * 2);
  unsigned short* hbuf = (unsigned short*)((char*)W2t + (size_t)NE * CPAD * HID * 2);
  // ybufFront (2 partials, 75.5MB) aliases xb+W1t (83.9MB) — both dead before
  // GEMM2; never reaches W2t/hbuf. ybufBack (2 partials) after hbuf — total
  // workspace need = 377.6MB, identical to R4's proven-passing budget.
  unsigned short* ybufFront = (unsigned short*)big;
  unsigned short* ybufBack = (unsigned short*)((char*)hbuf + (size_t)PAIR_CAP * HID * 2);
  size_t need = (size_t)(((char*)ybufBack + (size_t)2 * PAIR_CAP * CPAD * 2) - (char*)d_ws);
  if (ws_size < need) {
    k_sentinel<<<1, 64, 0, stream>>>(out);
    return;
  }

  k_gate<<<PART_BLOCKS, 256, 0, stream>>>(x, Wg, bg, part, topk_e, topk_w,
                                          (ushort4*)xb);
  k_setup<<<1, 1024, 0, stream>>>(topk_e, offsets_pad, cursor, part, pair_token,
                                  out + (size_t)B_TOK * CLS);
  k_scatter<<<B_TOK / 256, 256, 0, stream>>>(topk_e, cursor, pair_token, pos_of);

  k_trans_w1<<<dim3(HID / 64, DIN / 64, NE), 256, 0, stream>>>(W1, W1t);
  k_trans_w2<<<dim3(CPAD / 64, HID / 64, NE), 256, 0, stream>>>(W2, W2t);

  // GEMM1: h = relu(xb[gather] @ W1t^T + b1)   M=PAIR_CAP N=HID K=DIN
  k_gemm256<DIN / 64, DIN * 2, DIN * 2, true, 0, HID, HID, HID, 1>
      <<<dim3(HID / 256, PAIR_CAP / 256), 512, 0, stream>>>(
          xb, W1t, b1, pair_token, offsets_pad, hbuf, nullptr, (size_t)HID * DIN);

  // GEMM2: y = hbuf @ W2t^T + b2 (bf16 partials), K-split x4 for CU packing
  // (71% -> 85%): grid 16x72 = 1088 active blocks on 256 CUs.
  k_gemm256<HID / 256, HID * 2, HID * 2, false, 1, CLS, CPAD, CLS, 4>
      <<<dim3((CPAD / 256) * 4, PAIR_CAP / 256), 512, 0, stream>>>(
          hbuf, W2t, b2, pair_token, offsets_pad, ybufFront, ybufBack, (size_t)CPAD * HID);

  k_combine<<<B_TOK, 256, 0, stream>>>(ybufFront, ybufBack, pos_of, topk_w, out);
}

// Round 13
// 496.251 us; speedup vs baseline: 1.2042x; 1.0697x over previous
//
#include <hip/hip_runtime.h>
#include <hip/hip_bf16.h>
#include <cstdint>

#define B_TOK 8192
#define DIN   1024
#define HID   4096
#define CLS   1000
#define CPAD  1024
#define NE    8
#define PAIR_CAP 18432           // 16384 + 8*256, multiple of 256
#define PART_BLOCKS 2048

typedef __attribute__((ext_vector_type(8))) short short8;
typedef __attribute__((ext_vector_type(4))) float floatx4;

__device__ __forceinline__ unsigned short f2bf(float f) {
  unsigned int u = __builtin_bit_cast(unsigned int, f);
  u += 0x7fffu + ((u >> 16) & 1u);   // RNE
  return (unsigned short)(u >> 16);
}

__device__ __forceinline__ float bf2f(unsigned short u) {
  return __builtin_bit_cast(float, (unsigned int)u << 16);
}

__device__ __forceinline__ void gload16(const void* g, void* l) {
  __builtin_amdgcn_global_load_lds(
      (const __attribute__((address_space(1))) void*)(uintptr_t)g,
      (__attribute__((address_space(3))) void*)(unsigned int)(uintptr_t)l,
      16, 0, 0);
}

#define BARRIER()  asm volatile("s_barrier" ::: "memory")
#define VMCNT8()   asm volatile("s_waitcnt vmcnt(8)" ::: "memory")
#define VMCNT0()   asm volatile("s_waitcnt vmcnt(0)" ::: "memory")
#define LGKMCNT0() asm volatile("s_waitcnt lgkmcnt(0)" ::: "memory")

// swizzled LDS read: 16B at (row, byte-in-row), XOR-swizzle on 16B slot
__device__ __forceinline__ short8 ldsrd(const unsigned short* buf, int row, int bir) {
  const char* p = (const char*)buf + row * 128 + (bir ^ ((row & 7) << 4));
  return *(const short8*)p;
}

// ---------------- gating: one wave per token (fused x -> bf16 cast; NO global atomics) ----------------
__global__ void k_gate(const float* __restrict__ x, const float* __restrict__ Wg,
                       const float* __restrict__ bg,
                       float* __restrict__ part, int* __restrict__ topk_e,
                       float* __restrict__ topk_w, ushort4* __restrict__ xb4) {
  int tok = (blockIdx.x * blockDim.x + threadIdx.x) >> 6;
  int lane = threadIdx.x & 63;
  __shared__ float psum[NE];
  if (threadIdx.x < NE) psum[threadIdx.x] = 0.f;
  __syncthreads();

  float acc[NE];
#pragma unroll
  for (int e = 0; e < NE; e++) acc[e] = 0.f;
  const float4* xr4 = (const float4*)(x + (size_t)tok * DIN);
#pragma unroll
  for (int i = 0; i < 4; i++) {
    int d4 = lane + i * 64;
    float4 v = xr4[d4];
    ushort4 o;
    o.x = f2bf(v.x); o.y = f2bf(v.y); o.z = f2bf(v.z); o.w = f2bf(v.w);
    xb4[(size_t)tok * (DIN / 4) + d4] = o;
    float vs[4] = {v.x, v.y, v.z, v.w};
#pragma unroll
    for (int c = 0; c < 4; c++) {
      const float4* wr4 = (const float4*)(Wg + (size_t)(d4 * 4 + c) * NE);
      float4 wa = wr4[0], wb = wr4[1];
      float xv = vs[c];
      acc[0] += xv * wa.x; acc[1] += xv * wa.y; acc[2] += xv * wa.z; acc[3] += xv * wa.w;
      acc[4] += xv * wb.x; acc[5] += xv * wb.y; acc[6] += xv * wb.z; acc[7] += xv * wb.w;
    }
  }
#pragma unroll
  for (int e = 0; e < NE; e++)
    for (int off = 32; off; off >>= 1) acc[e] += __shfl_xor(acc[e], off);

  if (lane == 0) {
    float p[NE];
    float m = -1e30f;
#pragma unroll
    for (int e = 0; e < NE; e++) { p[e] = acc[e] + bg[e]; m = fmaxf(m, p[e]); }
    float s = 0.f;
#pragma unroll
    for (int e = 0; e < NE; e++) { p[e] = expf(p[e] - m); s += p[e]; }
    float inv = 1.f / s;
#pragma unroll
    for (int e = 0; e < NE; e++) p[e] *= inv;
    int e0 = 0;
#pragma unroll
    for (int e = 1; e < NE; e++) if (p[e] > p[e0]) e0 = e;
    int e1 = -1;
#pragma unroll
    for (int e = 0; e < NE; e++) {
      if (e == e0) continue;
      if (e1 < 0 || p[e] > p[e1]) e1 = e;
    }
    float wi = 1.f / (p[e0] + p[e1]);
    topk_e[tok * 2] = e0;  topk_e[tok * 2 + 1] = e1;
    topk_w[tok * 2] = p[e0] * wi;  topk_w[tok * 2 + 1] = p[e1] * wi;
#pragma unroll
    for (int e = 0; e < NE; e++) atomicAdd(&psum[e], p[e]);   // LDS only
  }
  __syncthreads();
  if (threadIdx.x < NE) part[blockIdx.x * NE + threadIdx.x] = psum[threadIdx.x];
}

// ---------------- setup: histogram counts, offsets (256-pad), cursors, lb_loss, dummy fill ----------------
__global__ void k_setup(const int* __restrict__ topk_e, int* __restrict__ offsets_pad,
                        int* __restrict__ cursor, const float* __restrict__ part,
                        int* __restrict__ pair_token, float* __restrict__ out_lb) {
  __shared__ int scnt[NE];
  __shared__ int soff[NE + 1];
  __shared__ float ssum[NE];
  int t = threadIdx.x;            // 1024 threads
  int lane = t & 63;
  if (t < NE) { scnt[t] = 0; ssum[t] = 0.f; }
  __syncthreads();
  for (int i = t; i < B_TOK * 2; i += 1024) atomicAdd(&scnt[topk_e[i]], 1);
  float loc[NE];
#pragma unroll
  for (int e = 0; e < NE; e++) loc[e] = 0.f;
  for (int i = t; i < PART_BLOCKS; i += 1024)
#pragma unroll
    for (int e = 0; e < NE; e++) loc[e] += part[i * NE + e];
#pragma unroll
  for (int e = 0; e < NE; e++)
    for (int off = 32; off; off >>= 1) loc[e] += __shfl_xor(loc[e], off);
  if (lane == 0)
#pragma unroll
    for (int e = 0; e < NE; e++) atomicAdd(&ssum[e], loc[e]);
  __syncthreads();
  if (t == 0) {
    float lb = 0.f;
    for (int e = 0; e < NE; e++) {
      float mean = ssum[e] / (float)B_TOK;
      lb += mean * mean;
    }
    *out_lb = lb * (float)NE;
    int off = 0;
    for (int e = 0; e < NE; e++) {
      soff[e] = off;
      off += ((scnt[e] + 255) >> 8) << 8;
    }
    soff[NE] = off;
  }
  __syncthreads();
  if (t <= NE) offsets_pad[t] = soff[t];
  if (t < NE) cursor[t] = soff[t];
  for (int e = 0; e < NE; e++) {
    int s0 = soff[e] + scnt[e], s1 = soff[e + 1];
    for (int i = s0 + t; i < s1; i += 1024) pair_token[i] = 0;
  }
}

// ---------------- scatter: hierarchical (LDS local ranks, 8 global atomics/block) ----------------
__global__ void k_scatter(const int* __restrict__ topk_e, int* __restrict__ cursor,
                          int* __restrict__ pair_token, int* __restrict__ pos_of) {
  __shared__ int lcnt[NE], lbase[NE];
  int t = threadIdx.x;
  if (t < NE) lcnt[t] = 0;
  __syncthreads();
  int b = blockIdx.x * 256 + t;
  int ea = topk_e[b * 2], eb = topk_e[b * 2 + 1];
  int ra = atomicAdd(&lcnt[ea], 1);
  int rb = atomicAdd(&lcnt[eb], 1);
  __syncthreads();
  if (t < NE) lbase[t] = atomicAdd(&cursor[t], lcnt[t]);
  __syncthreads();
  int pa = lbase[ea] + ra, pb = lbase[eb] + rb;
  pair_token[pa] = b;  pos_of[b * 2] = pa;
  pair_token[pb] = b;  pos_of[b * 2 + 1] = pb;
}

// ---------------- merged transpose+cast for W1 and W2 (one launch) ----------------
// z < 8 : W1 expert z : [DIN][HID] f32 -> [HID][DIN] bf16   (n0=bx*64, k0=by*64)
// z >= 8: W2 expert z-8: [HID][CLS] f32 -> [CPAD][HID] bf16 (n0=by*64, k0=bx*64)
__global__ void k_trans_w(const float* __restrict__ W1, unsigned short* __restrict__ W1t,
                          const float* __restrict__ W2, unsigned short* __restrict__ W2t) {
  __shared__ float tile[64][65];
  int z = blockIdx.z;
  int t = threadIdx.x;
  int r = t >> 4, c4 = (t & 15) * 4;
  int wk = (t & 15) * 4, n = t >> 4;

  if (z < 8) {
    int e = z, n0 = blockIdx.x * 64, k0 = blockIdx.y * 64;
    const float* src = W1 + ((size_t)e * DIN + k0) * HID + n0;
#pragma unroll
    for (int p = 0; p < 4; p++) {
      int k = r + p * 16;
      float4 v = *(const float4*)&src[(size_t)k * HID + c4];
      tile[k][c4] = v.x; tile[k][c4 + 1] = v.y; tile[k][c4 + 2] = v.z; tile[k][c4 + 3] = v.w;
    }
    __syncthreads();
    unsigned short* dst = W1t + ((size_t)e * HID + n0) * DIN + k0;
#pragma unroll
    for (int p = 0; p < 4; p++) {
      int nn = n + p * 16;
      ushort4 o;
      o.x = f2bf(tile[wk][nn]);     o.y = f2bf(tile[wk + 1][nn]);
      o.z = f2bf(tile[wk + 2][nn]); o.w = f2bf(tile[wk + 3][nn]);
      *(ushort4*)&dst[(size_t)nn * DIN + wk] = o;
    }
  } else {
    int e = z - 8, n0 = blockIdx.y * 64, k0 = blockIdx.x * 64;
    const float* src = W2 + ((size_t)e * HID + k0) * CLS + n0;
    if (n0 + 64 <= CLS) {
#pragma unroll
      for (int p = 0; p < 4; p++) {
        int k = r + p * 16;
        float4 v = *(const float4*)&src[(size_t)k * CLS + c4];
        tile[k][c4] = v.x; tile[k][c4 + 1] = v.y; tile[k][c4 + 2] = v.z; tile[k][c4 + 3] = v.w;
      }
    } else {
#pragma unroll
      for (int p = 0; p < 4; p++) {
        int k = r + p * 16;
#pragma unroll
        for (int c = 0; c < 4; c++) {
          int nn = n0 + c4 + c;
          tile[k][c4 + c] = (nn < CLS) ? src[(size_t)k * CLS + c4 + c] : 0.f;
        }
      }
    }
    __syncthreads();
    unsigned short* dst = W2t + ((size_t)e * CPAD + n0) * HID + k0;
#pragma unroll
    for (int p = 0; p < 4; p++) {
      int nn = n + p * 16;
      ushort4 o;
      o.x = f2bf(tile[wk][nn]);     o.y = f2bf(tile[wk + 1][nn]);
      o.z = f2bf(tile[wk + 2][nn]); o.w = f2bf(tile[wk + 3][nn]);
      *(ushort4*)&dst[(size_t)nn * HID + wk] = o;
    }
  }
}

// ================= 256x256 grouped GEMM, single-barrier K-loop (R10, proven) =================
// KSPLIT=2: ks=0 -> outp, ks=1 -> outp2.
template<int NT, int A_ROW_BYTES, int B_ROW_BYTES, bool GATHER, int OUT_MODE,
         int BIAS_STRIDE, int OUT_STRIDE, int NCOLS_VALID, int KSPLIT>
__global__ __launch_bounds__(512, 2)
void k_gemm256(const unsigned short* __restrict__ Amat,
               const unsigned short* __restrict__ Bmat,
               const float* __restrict__ bias,
               const int* __restrict__ pair_token,
               const int* __restrict__ offsets_pad,
               void* __restrict__ outp,
               void* __restrict__ outp2,
               size_t b_expert_stride) {
  const int tid = threadIdx.x;
  const int lane = tid & 63;
  const int w = tid >> 6;            // wave 0..7
  const int wm = w >> 2;             // 0..1
  const int wn = w & 3;              // 0..3

  const int nwg = gridDim.x * gridDim.y;
  const int orig = blockIdx.y * gridDim.x + blockIdx.x;
  const int wg = (orig & 7) * (nwg >> 3) + (orig >> 3);
  int bx = wg % gridDim.x;
  const int by = wg / gridDim.x;

  const int p0 = by * 256;
  if (p0 >= offsets_pad[NE]) return;

  int ks = 0;
  if constexpr (KSPLIT == 2) { ks = bx & 1; bx >>= 1; }
  const int n0 = bx * 256;
  const size_t kb = (size_t)ks * NT * 128;   // byte offset into a row

  int e = 0;
#pragma unroll
  for (int i = 1; i < NE; i++) if (p0 >= offsets_pad[i]) e = i;

  __shared__ alignas(16) unsigned short sA[2 * 256 * 64];   // 64 KiB
  __shared__ alignas(16) unsigned short sB[2 * 256 * 64];   // 64 KiB

  const int rl = lane >> 3;                 // 0..7
  const int swz16 = ((lane & 7) ^ rl) << 4; // pre-swizzled 16B slot
  const int frow = lane & 15;
  const int fkb = (lane >> 4) << 4;         // byte offset of k-chunk

  const char* asrc[2][2];
  const char* bsrc[2][2];
  const char* Bexp = (const char*)(Bmat + (size_t)e * b_expert_stride);
#pragma unroll
  for (int h = 0; h < 2; h++)
#pragma unroll
    for (int i = 0; i < 2; i++) {
      int r = h * 128 + w * 16 + i * 8 + rl;
      if constexpr (GATHER) {
        int tk = pair_token[p0 + r];
        asrc[h][i] = (const char*)Amat + (size_t)tk * A_ROW_BYTES + swz16;
      } else {
        asrc[h][i] = (const char*)Amat + (size_t)(p0 + r) * A_ROW_BYTES + swz16;
      }
      bsrc[h][i] = Bexp + (size_t)(n0 + r) * B_ROW_BYTES + swz16;
    }

  floatx4 acc[8][4];
#pragma unroll
  for (int i = 0; i < 8; i++)
#pragma unroll
    for (int j = 0; j < 4; j++) acc[i][j] = (floatx4){0.f, 0.f, 0.f, 0.f};

#define STAGE_A(h, dst, koff)                                            \
  gload16(asrc[h][0] + (koff), (dst) + ((h) * 128 + w * 16 + 0) * 64);   \
  gload16(asrc[h][1] + (koff), (dst) + ((h) * 128 + w * 16 + 8) * 64);
#define STAGE_B(h, dst, koff)                                            \
  gload16(bsrc[h][0] + (koff), (dst) + ((h) * 128 + w * 16 + 0) * 64);   \
  gload16(bsrc[h][1] + (koff), (dst) + ((h) * 128 + w * 16 + 8) * 64);

  // prologue
  STAGE_B(0, sB, kb); STAGE_B(1, sB, kb);
  STAGE_A(0, sA, kb); STAGE_A(1, sA, kb);
  STAGE_B(0, sB + 16384, kb + 128); STAGE_B(1, sB + 16384, kb + 128);
  STAGE_A(0, sA + 16384, kb + 128); STAGE_A(1, sA + 16384, kb + 128);
  VMCNT8();
  BARRIER();

#define RD_A(dst, mh, buf)                                                    \
  _Pragma("unroll") for (int mi = 0; mi < 4; mi++)                            \
  _Pragma("unroll") for (int kk = 0; kk < 2; kk++)                            \
    dst[mi][kk] = ldsrd(buf, wm * 128 + (mh) * 64 + mi * 16 + frow, kk * 64 + fkb);
#define RD_B(dst, nh, buf)                                                    \
  _Pragma("unroll") for (int ni = 0; ni < 2; ni++)                            \
  _Pragma("unroll") for (int kk = 0; kk < 2; kk++)                            \
    dst[ni][kk] = ldsrd(buf, wn * 64 + (nh) * 32 + ni * 16 + frow, kk * 64 + fkb);
#define MFMA_Q(fa, fb, mh, nh)                                                \
  _Pragma("unroll") for (int mi = 0; mi < 4; mi++)                            \
  _Pragma("unroll") for (int ni = 0; ni < 2; ni++)                            \
  _Pragma("unroll") for (int kk = 0; kk < 2; kk++)                            \
    acc[(mh) * 4 + mi][(nh) * 2 + ni] = __builtin_amdgcn_mfma_f32_16x16x32_bf16( \
        fa[mi][kk], fb[ni][kk], acc[(mh) * 4 + mi][(nh) * 2 + ni], 0, 0, 0);

  short8 a[4][2], b0[2][2], b1[2][2];
  RD_A(a, 0, sA); RD_B(b0, 0, sB);

  for (int t = 0; t < NT; ++t) {
    const int cur = t & 1;
    unsigned short* pA = sA + cur * 16384;
    unsigned short* pB = sB + cur * 16384;
    unsigned short* nA = sA + (cur ^ 1) * 16384;
    unsigned short* nB = sB + (cur ^ 1) * 16384;
    const bool s1 = (t + 1 < NT);
    const bool s2 = (t + 2 < NT);
    const size_t off2 = kb + (size_t)(t + 2) * 128;

    MFMA_Q(a, b0, 0, 0);
    RD_B(b1, 1, pB);

    MFMA_Q(a, b1, 0, 1);
    RD_A(a, 1, pA);
    VMCNT0();
    LGKMCNT0();
    BARRIER();

    MFMA_Q(a, b1, 1, 1);
    if (s2) { STAGE_B(0, pB, off2); STAGE_B(1, pB, off2); }

    MFMA_Q(a, b0, 1, 0);
    if (s1) { RD_B(b0, 0, nB); RD_A(a, 0, nA); }
    if (s2) { STAGE_A(0, pA, off2); STAGE_A(1, pA, off2); }
  }
#undef RD_A
#undef RD_B
#undef MFMA_Q
#undef STAGE_A
#undef STAGE_B

  // epilogue (bf16 out both modes)
  const int cl = lane & 15;
  const int rj = (lane >> 4) * 4;
  const int ocol0 = n0 + wn * 64;
  const int orow0 = p0 + wm * 128;
  unsigned short* out = (unsigned short*)outp;
  if constexpr (KSPLIT == 2) { if (ks) out = (unsigned short*)outp2; }
#pragma unroll
  for (int ni = 0; ni < 4; ni++) {
    int col = ocol0 + ni * 16 + cl;
    float bv = (ks == 0 && col < NCOLS_VALID) ? bias[e * BIAS_STRIDE + col] : 0.f;
#pragma unroll
    for (int mi = 0; mi < 8; mi++) {
      size_t rbase = (size_t)(orow0 + mi * 16 + rj) * OUT_STRIDE + col;
#pragma unroll
      for (int j = 0; j < 4; j++) {
        float v = acc[mi][ni][j] + bv;
        if constexpr (OUT_MODE == 0) v = fmaxf(v, 0.f);
        out[rbase + (size_t)j * OUT_STRIDE] = f2bf(v);
      }
    }
  }
}

// ---------------- combine (bf16 partials, 2 buffers) ----------------
__global__ void k_combine(const unsigned short* __restrict__ yA,
                          const unsigned short* __restrict__ yB,
                          const int* __restrict__ pos_of, const float* __restrict__ topk_w,
                          float* __restrict__ out) {
  int b = blockIdx.x, t = threadIdx.x;
  if (t >= 250) return;   // 250 x 4 = 1000 cols
  int q0 = pos_of[b * 2], q1 = pos_of[b * 2 + 1];
  float w0 = topk_w[b * 2], w1 = topk_w[b * 2 + 1];
  const ushort4 a0 = *(const ushort4*)(yA + (size_t)q0 * CPAD + t * 4);
  const ushort4 c0 = *(const ushort4*)(yB + (size_t)q0 * CPAD + t * 4);
  const ushort4 a1 = *(const ushort4*)(yA + (size_t)q1 * CPAD + t * 4);
  const ushort4 c1 = *(const ushort4*)(yB + (size_t)q1 * CPAD + t * 4);
  float4 r;
  r.x = w0 * (bf2f(a0.x) + bf2f(c0.x)) + w1 * (bf2f(a1.x) + bf2f(c1.x));
  r.y = w0 * (bf2f(a0.y) + bf2f(c0.y)) + w1 * (bf2f(a1.y) + bf2f(c1.y));
  r.z = w0 * (bf2f(a0.z) + bf2f(c0.z)) + w1 * (bf2f(a1.z) + bf2f(c1.z));
  r.w = w0 * (bf2f(a0.w) + bf2f(c0.w)) + w1 * (bf2f(a1.w) + bf2f(c1.w));
  ((float4*)(out + (size_t)b * CLS))[t] = r;
}

__global__ void k_sentinel(float* out) { if (threadIdx.x == 0) out[0] = 1.0e9f; }

extern "C" void kernel_launch(void* const* d_in, const int* in_sizes, int n_in,
                              void* d_out, int out_size, void* d_ws, size_t ws_size,
                              hipStream_t stream) {
  const float* x  = (const float*)d_in[0];
  const float* Wg = (const float*)d_in[1];
  const float* bg = (const float*)d_in[2];
  const float* W1 = (const float*)d_in[3];
  const float* b1 = (const float*)d_in[4];
  const float* W2 = (const float*)d_in[5];
  const float* b2 = (const float*)d_in[6];
  float* out = (float*)d_out;

  char* w = (char*)d_ws;
  int* offsets_pad = (int*)w;  w += 256;
  int* cursor = (int*)w;       w += 256;
  float* part = (float*)w;     w += (size_t)PART_BLOCKS * NE * 4;
  int* topk_e = (int*)w;       w += (size_t)B_TOK * 2 * 4;
  float* topk_w = (float*)w;   w += (size_t)B_TOK * 2 * 4;
  int* pos_of = (int*)w;       w += (size_t)B_TOK * 2 * 4;
  int* pair_token = (int*)w;   w += (size_t)PAIR_CAP * 4;
  char* big = w;
  unsigned short* xb  = (unsigned short*)big;
  unsigned short* W1t = (unsigned short*)(big + (size_t)B_TOK * DIN * 2);
  unsigned short* W2t = (unsigned short*)((char*)W1t + (size_t)NE * HID * DIN * 2);
  unsigned short* hbuf = (unsigned short*)((char*)W2t + (size_t)NE * CPAD * HID * 2);
  unsigned short* ybufB = (unsigned short*)((char*)hbuf + (size_t)PAIR_CAP * HID * 2);
  // ybufA (bf16, 37.7MB) aliases xb+W1t front region (80MB); both dead
  // before GEMM2 runs; never reaches W2t/hbuf. ks=1 partials -> ybufB.
  unsigned short* ybufA = (unsigned short*)big;
  size_t need = (size_t)(((char*)ybufB + (size_t)PAIR_CAP * CPAD * 2) - (char*)d_ws);
  if (ws_size < need) {
    k_sentinel<<<1, 64, 0, stream>>>(out);
    return;
  }

  k_gate<<<PART_BLOCKS, 256, 0, stream>>>(x, Wg, bg, part, topk_e, topk_w,
                                          (ushort4*)xb);
  k_setup<<<1, 1024, 0, stream>>>(topk_e, offsets_pad, cursor, part, pair_token,
                                  out + (size_t)B_TOK * CLS);
  k_scatter<<<B_TOK / 256, 256, 0, stream>>>(topk_e, cursor, pair_token, pos_of);

  // merged W1+W2 transpose/cast: z<8 -> W1 expert z; z>=8 -> W2 expert z-8
  k_trans_w<<<dim3(64, 16, 16), 256, 0, stream>>>(W1, W1t, W2, W2t);

  // GEMM1: h = relu(xb[gather] @ W1t^T + b1)   M=PAIR_CAP N=HID K=DIN
  k_gemm256<DIN / 64, DIN * 2, DIN * 2, true, 0, HID, HID, HID, 1>
      <<<dim3(HID / 256, PAIR_CAP / 256), 512, 0, stream>>>(
          xb, W1t, b1, pair_token, offsets_pad, hbuf, nullptr, (size_t)HID * DIN);

  // GEMM2: y = hbuf @ W2t^T + b2 (bf16 partials), K-split x2 (proven R10 config)
  k_gemm256<HID / 128, HID * 2, HID * 2, false, 1, CLS, CPAD, CLS, 2>
      <<<dim3((CPAD / 256) * 2, PAIR_CAP / 256), 512, 0, stream>>>(
          hbuf, W2t, b2, pair_token, offsets_pad, ybufA, ybufB, (size_t)CPAD * HID);

  k_combine<<<B_TOK, 256, 0, stream>>>(ybufA, ybufB, pos_of, topk_w, out);
}